// Round 12
// baseline (372.602 us; speedup 1.0000x reference)
//
#include <hip/hip_runtime.h>
#include <hip/hip_bf16.h>

// ---------------------------------------------------------------------------
// ScaleDotProductAttention: q=Q@Wq^T+bq; k=K@Wk^T+bk; v=V@Wv^T+bv
// S = q@k^T/32 (mask==1 -> -inf), P=softmax(S), out = P@v
// B=8, L1=L2=2048, D=E=1024. bf16 MFMA 16x16x32, fp32 accum.
// Round 12: eliminate the Q/K/V fp32->bf16 convert pass (~45us of pure
// dtype traffic). Projections stage A as FP32 directly via global_load_lds
// (the proven async path — NOT the twice-failed reg-staging), converting
// LDS->reg at fragment load with v_cvt_pk_bf16_f32 (RNE, bit-identical).
// LDS plan: A fp32 3x32KB rotating half-slots + B bf16 3x16KB = 144KB;
// phase->row mapping lets h0 die after q1; ledger: vmcnt(6) mid, vmcnt(4)
// end, all staging >=4 phases ahead. qk/pv/softmax unchanged from r11.
// ---------------------------------------------------------------------------

using u16 = unsigned short;
using frag_ab = __attribute__((ext_vector_type(8))) short;   // 8 bf16 (4 VGPRs)
using frag_cd = __attribute__((ext_vector_type(4))) float;   // 4 fp32

#define BAR() asm volatile("s_barrier" ::: "memory")
#define WAITV(n) asm volatile("s_waitcnt vmcnt(" #n ")" ::: "memory")
#define WAITLGKM0() do { asm volatile("s_waitcnt lgkmcnt(0)" ::: "memory"); \
                         __builtin_amdgcn_sched_barrier(0); } while (0)
#define L(d, ab, h) (lds + (((d) * 4) + ((ab) * 2) + (h)) * 8192)

__device__ __forceinline__ u16 f2bf(float f) {
  union { float f; unsigned u; } c; c.f = f;
  unsigned u = c.u;
  return (u16)((u + 0x7FFFu + ((u >> 16) & 1u)) >> 16);   // RNE
}
__device__ __forceinline__ u16 f2h(float f) {
  union { _Float16 h; u16 u; } c; c.h = (_Float16)f; return c.u;
}
__device__ __forceinline__ float h2f(u16 u) {
  union { u16 u; _Float16 h; } c; c.u = u; return (float)c.h;
}

// 8 fp32 -> bf16x8 via v_cvt_pk_bf16_f32 (RNE; matches f2bf bit-exactly)
__device__ __forceinline__ frag_ab pack8f(float4 a, float4 b) {
  union { __hip_bfloat162 h; unsigned u; } c0, c1, c2, c3;
  c0.h = __float22bfloat162_rn(make_float2(a.x, a.y));
  c1.h = __float22bfloat162_rn(make_float2(a.z, a.w));
  c2.h = __float22bfloat162_rn(make_float2(b.x, b.y));
  c3.h = __float22bfloat162_rn(make_float2(b.z, b.w));
  union { frag_ab f; unsigned u[4]; } r;
  r.u[0] = c0.u; r.u[1] = c1.u; r.u[2] = c2.u; r.u[3] = c3.u;
  return r.f;
}

__device__ __forceinline__ void async_ld16(const void* g, void* l) {
  __builtin_amdgcn_global_load_lds(
      (const __attribute__((address_space(1))) unsigned*)g,
      (__attribute__((address_space(3))) unsigned*)l, 16, 0, 0);
}

// weights fp32 -> bf16, one 3-way dispatch
__global__ void cvtw3(const float* __restrict__ a, const float* __restrict__ b,
                      const float* __restrict__ c, u16* __restrict__ out) {
  const float* in = blockIdx.z == 0 ? a : (blockIdx.z == 1 ? b : c);
  u16* o = out + (long)blockIdx.z * 1048576L;
  long i = ((long)blockIdx.x * 256 + threadIdx.x) * 4;
  float4 v = *reinterpret_cast<const float4*>(in + i);
  *reinterpret_cast<ushort4*>(o + i) =
      make_ushort4(f2bf(v.x), f2bf(v.y), f2bf(v.z), f2bf(v.w));
}

// Stage one 128x64 bf16 half-tile via global_load_lds (linear dest,
// 3-bit XOR swizzle pre-applied to the GLOBAL source 16B-slot).
__device__ __forceinline__ void stage_half(const u16* __restrict__ g_rowbase,
                                           long Kstr, u16* l_half,
                                           int wave, int lane) {
  const int t = wave * 64 + lane;
  #pragma unroll
  for (int i = 0; i < 2; i++) {
    const int row = i * 64 + (t >> 3);
    const int cb  = (t & 7) * 16;
    const int cbs = cb ^ ((row & 7) << 4);
    async_ld16(g_rowbase + (long)row * Kstr + (cbs >> 1),
               l_half + i * 4096 + wave * 512);
  }
}

// Stage one fp32 A-half (128 half-rows x 64 floats, 32KB) via global_load_lds.
// Half h holds tile rows {h*64..h*64+63} U {128+h*64..128+h*64+63}:
// half-row rp -> tile row (rp&63) + ((rp>>6)<<7) + h*64.
// 16B-slot XOR swizzle (rp&7) pre-applied to the global source.
__device__ __forceinline__ void stage_f32(const float* __restrict__ g, int hsel,
                                          float* dst, int tid) {
  #pragma unroll
  for (int i = 0; i < 4; i++) {
    const int rp = i * 32 + (tid >> 4);
    const int row = (rp & 63) + ((rp >> 6) << 7) + hsel * 64;
    const int ss = (tid & 15) ^ (rp & 7);
    async_ld16(g + (long)row * 1024 + ss * 4,
               dst + i * 2048 + (tid >> 6) * 256);
  }
}

// swizzled fragment read: 8 bf16 at (row r, k..k+7) of a [128][64] bf16 half
__device__ __forceinline__ frag_ab ld_frag(const u16* half_base, int r, int k) {
  const int idx = r * 64 + (k ^ ((r & 7) << 3));
  return *reinterpret_cast<const frag_ab*>(half_base + idx);
}

// swizzled float4 read from a [128][64-float] fp32 half; s = 16B slot
__device__ __forceinline__ float4 ld4f(const float* half, int rp, int s) {
  return *reinterpret_cast<const float4*>(half + rp * 64 + ((s ^ (rp & 7)) << 2));
}

// Bijective XCD swizzle over the FULL grid (z folded in)
struct SwzOut { int z, m0, n0; };
__device__ __forceinline__ SwzOut grid_swizzle() {
  const int gx = gridDim.x, gy = gridDim.y, gz = gridDim.z;
  const int nwg = gx * gy * gz;
  const int lin = ((int)blockIdx.z * gy + blockIdx.y) * gx + blockIdx.x;
  const int q8 = nwg >> 3, r8 = nwg & 7;
  const int xcd = lin & 7, idx8 = lin >> 3;
  const int swz = (xcd < r8 ? xcd * (q8 + 1) : r8 * (q8 + 1) + (xcd - r8) * q8) + idx8;
  SwzOut o;
  o.z = swz / (gx * gy);
  const int rem = swz % (gx * gy);
  o.m0 = (rem / gx) * 256;
  o.n0 = (rem % gx) * 256;
  return o;
}

#define MFMA_PAIR(base)                                                        \
  __builtin_amdgcn_s_setprio(1);                                              \
  _Pragma("unroll")                                                           \
  for (int am = 0; am < 2; ++am)                                              \
    _Pragma("unroll")                                                         \
    for (int bn = 0; bn < 4; ++bn)                                            \
      _Pragma("unroll")                                                       \
      for (int kk = 0; kk < 2; ++kk)                                          \
        acc[(base) + am][bn] = __builtin_amdgcn_mfma_f32_16x16x32_bf16(       \
            af[am][kk], bf[bn][kk], acc[(base) + am][bn], 0, 0, 0);           \
  __builtin_amdgcn_s_setprio(0);

// ===== bf16 GEMM core (qk / pv), unchanged from round 11 =====
__device__ __forceinline__ void
gemm256_core(int out_mode, const u16* __restrict__ Ab, const u16* __restrict__ Bb,
             void* __restrict__ Cb, const float* __restrict__ bias,
             int N, int K, int m0, int n0, float scale, u16* lds)
{
  const int tid = threadIdx.x;
  const int wave = tid >> 6, lane = tid & 63;
  const int wm = wave >> 2, wn = wave & 3;
  const int ln15 = lane & 15, kof = (lane >> 4) * 8;
  const int rB0 = (wn & 1) * 64;
  const int NT = K >> 6;

  frag_cd acc[8][4];
  #pragma unroll
  for (int i = 0; i < 8; i++)
    #pragma unroll
    for (int j = 0; j < 4; j++)
      acc[i][j] = (frag_cd){0.f, 0.f, 0.f, 0.f};

  stage_half(Ab + (long)(m0 +   0) * K, K, L(0, 0, 0), wave, lane);
  stage_half(Ab + (long)(m0 + 128) * K, K, L(0, 0, 1), wave, lane);
  stage_half(Bb + (long)(n0 +   0) * K, K, L(0, 1, 0), wave, lane);
  stage_half(Bb + (long)(n0 + 128) * K, K, L(0, 1, 1), wave, lane);
  {
    const int t1 = (1 < NT) ? 1 : 0;
    stage_half(Bb + (long)(n0 +   0) * K + t1 * 64, K, L(1, 1, 0), wave, lane);
    stage_half(Bb + (long)(n0 + 128) * K + t1 * 64, K, L(1, 1, 1), wave, lane);
  }
  WAITV(4);
  BAR();

  for (int t = 0; t < NT; ++t) {
    const int d = t & 1;
    const u16* Al = L(d, 0, wm);
    const u16* Bl = L(d, 1, wn >> 1);
    const int tA = (t + 1 < NT) ? t + 1 : NT - 1;
    const int tB = (t + 2 < NT) ? t + 2 : NT - 1;

    frag_ab bf[4][2], af[2][2];

    // q0
    #pragma unroll
    for (int bn = 0; bn < 4; ++bn)
      #pragma unroll
      for (int kk = 0; kk < 2; ++kk)
        bf[bn][kk] = ld_frag(Bl, rB0 + bn * 16 + ln15, kk * 32 + kof);
    #pragma unroll
    for (int am = 0; am < 2; ++am)
      #pragma unroll
      for (int kk = 0; kk < 2; ++kk)
        af[am][kk] = ld_frag(Al, am * 16 + ln15, kk * 32 + kof);
    stage_half(Ab + (long)(m0 +   0) * K + tA * 64, K, L(d ^ 1, 0, 0), wave, lane);
    stage_half(Ab + (long)(m0 + 128) * K + tA * 64, K, L(d ^ 1, 0, 1), wave, lane);
    BAR();
    MFMA_PAIR(0)
    BAR();

    // q1
    #pragma unroll
    for (int am = 0; am < 2; ++am)
      #pragma unroll
      for (int kk = 0; kk < 2; ++kk)
        af[am][kk] = ld_frag(Al, (2 + am) * 16 + ln15, kk * 32 + kof);
    stage_half(Bb + (long)(n0 + 0) * K + tB * 64, K, L(d, 1, 0), wave, lane);
    BAR();
    MFMA_PAIR(2)
    BAR();

    // q2
    #pragma unroll
    for (int am = 0; am < 2; ++am)
      #pragma unroll
      for (int kk = 0; kk < 2; ++kk)
        af[am][kk] = ld_frag(Al, (4 + am) * 16 + ln15, kk * 32 + kof);
    stage_half(Bb + (long)(n0 + 128) * K + tB * 64, K, L(d, 1, 1), wave, lane);
    BAR();
    MFMA_PAIR(4)
    BAR();

    // q3
    #pragma unroll
    for (int am = 0; am < 2; ++am)
      #pragma unroll
      for (int kk = 0; kk < 2; ++kk)
        af[am][kk] = ld_frag(Al, (6 + am) * 16 + ln15, kk * 32 + kof);
    BAR();
    MFMA_PAIR(6)
    WAITV(4);
    BAR();
  }

  WAITV(0);
  BAR();

  const int cl = lane & 15;
  const int rb = (lane >> 4) * 4;

  if (out_mode == 3) {
    // fp16 row-major via per-wave LDS transpose
    u16* Wt = lds + wave * 8192;
    #pragma unroll
    for (int am = 0; am < 8; ++am)
      #pragma unroll
      for (int bn = 0; bn < 4; ++bn) {
        const int col = bn * 16 + cl;
        #pragma unroll
        for (int r = 0; r < 4; ++r) {
          const int row = am * 16 + rb + r;
          const int slot = (col >> 3) ^ ((row >> 2) & 7);
          Wt[row * 64 + slot * 8 + (col & 7)] = f2h(acc[am][bn][r] * scale);
        }
      }
    WAITLGKM0();
    u16* Cp = (u16*)Cb;
    #pragma unroll
    for (int i = 0; i < 16; ++i) {
      const int row = (lane >> 3) + i * 8;
      const int c = lane & 7;
      const int slot = c ^ ((row >> 2) & 7);
      frag_ab v = *reinterpret_cast<const frag_ab*>(Wt + row * 64 + slot * 8);
      const long grow = m0 + wm * 128 + row;
      const int gcol = n0 + wn * 64 + c * 8;
      *reinterpret_cast<frag_ab*>(Cp + grow * N + gcol) = v;
    }
  } else {
    // fp32 row-major, 2 passes of 32 cols through LDS
    float* Wt = (float*)(void*)lds + wave * 4096;
    float* Cp = (float*)Cb;
    #pragma unroll
    for (int p = 0; p < 2; ++p) {
      #pragma unroll
      for (int am = 0; am < 8; ++am)
        #pragma unroll
        for (int bn = 0; bn < 2; ++bn) {
          const int col = bn * 16 + cl;
          #pragma unroll
          for (int r = 0; r < 4; ++r) {
            const int row = am * 16 + rb + r;
            const int slot = (col >> 2) ^ ((row >> 2) & 7);
            Wt[row * 32 + slot * 4 + (col & 3)] = acc[am][2 * p + bn][r] * scale;
          }
        }
      WAITLGKM0();
      #pragma unroll
      for (int i = 0; i < 16; ++i) {
        const int row = (lane >> 3) + i * 8;
        const int c = lane & 7;
        const int slot = c ^ ((row >> 2) & 7);
        float4 v = *reinterpret_cast<const float4*>(Wt + row * 32 + slot * 4);
        const long grow = m0 + wm * 128 + row;
        const int gcol = n0 + wn * 64 + p * 32 + c * 4;
        *reinterpret_cast<float4*>(Cp + grow * N + gcol) = v;
      }
      if (p == 0) WAITLGKM0();
    }
  }
}

__global__ void __launch_bounds__(512, 2)
qk_gemm(const u16* A, const u16* Bt, void* C,
        int M, int N, int K, long sA, long sB, long sC, float scale) {
  __shared__ u16 lds[8 * 8192];
  SwzOut s = grid_swizzle();
  gemm256_core(3, A + (long)s.z * sA, Bt + (long)s.z * sB,
               (u16*)C + (long)s.z * sC, nullptr, N, K, s.m0, s.n0, scale, lds);
}
__global__ void __launch_bounds__(512, 2)
pv_gemm(const u16* A, const u16* Bt, void* C,
        int M, int N, int K, long sA, long sB, long sC, float scale) {
  __shared__ u16 lds[8 * 8192];
  SwzOut s = grid_swizzle();
  gemm256_core(0, A + (long)s.z * sA, Bt + (long)s.z * sB,
               (float*)C + (long)s.z * sC, nullptr, N, K, s.m0, s.n0, scale, lds);
}

// ===== fused projections, fp32 A staged via global_load_lds =====
// LDS: A fp32 3 half-slots (32KB each, 96KB) + B bf16 3 half-slots (48KB).
// Phase->rows: q0/q1 compute am0-3 (A-half 0), q2/q3 am4-7 (A-half 1).
// Per-tile issues: q0 Ah0(t+1)[4]; q1 Bh0(t+1)[2]; q2 Bh1(t+1)[2]+Ah1(t+1)[4].
// Waits: vmcnt(6) before q1's trailing barrier (Ah1(t) landed);
//        vmcnt(4) before tile-end barrier (Ah0/Bh0/Bh1(t+1) landed).
#define AFP(s) ((float*)(void*)lds + (s) * 8192)
#define BHP(s) (lds + 49152 + (s) * 8192)

__global__ void __launch_bounds__(512, 1)
proj3f_gemm(const float* __restrict__ Qf, const float* __restrict__ Kf,
            const float* __restrict__ Vf, const u16* __restrict__ Wb,
            const float* __restrict__ bq, const float* __restrict__ bk,
            const float* __restrict__ bv, u16* __restrict__ qkb,
            u16* __restrict__ vT)
{
  __shared__ u16 lds[73728];   // 144 KB

  SwzOut s = grid_swizzle();   // grid (4, 64, 3)
  const float* Af = s.z == 0 ? Qf : (s.z == 1 ? Kf : Vf);
  const u16* W = Wb + (long)s.z * 1048576L;
  const float* bias = s.z == 0 ? bq : (s.z == 1 ? bk : bv);
  const int m0 = s.m0, n0 = s.n0;
  const float* Atile = Af + (long)m0 * 1024;

  const int tid = threadIdx.x;
  const int wave = tid >> 6, lane = tid & 63;
  const int wm = wave >> 2, wn = wave & 3;
  const int ln15 = lane & 15, kof = (lane >> 4) * 8;
  const int rB0 = (wn & 1) * 64;

  frag_cd acc[8][4];
  #pragma unroll
  for (int i = 0; i < 8; i++)
    #pragma unroll
    for (int j = 0; j < 4; j++)
      acc[i][j] = (frag_cd){0.f, 0.f, 0.f, 0.f};

  // prologue: Ah0(0), Bh0(0), Bh1(0), Ah1(0) (in this issue order)
  stage_f32(Atile, 0, AFP(0), tid);
  stage_half(W + (long)(n0 +   0) * 1024, 1024, BHP(0), wave, lane);
  stage_half(W + (long)(n0 + 128) * 1024, 1024, BHP(1), wave, lane);
  stage_f32(Atile, 1, AFP(1), tid);
  WAITV(4);   // Ah0(0)+B(0) landed; Ah1(0) (4 newest) in flight
  BAR();

  int a0 = 0, a1 = 1, a2 = 2;   // slots (2t)%3, (2t+1)%3, (2t+2)%3
  for (int t = 0; t < 16; ++t) {
    const int tn = (t + 1 < 16) ? t + 1 : 15;
    const float* Al0 = AFP(a0);
    const float* Al1 = AFP(a1);
    const u16* Bl = BHP((wn >> 1) ? a1 : a0);

    frag_ab bf[4][2], af[2][2];

    // q0: bf(t) 8 + af am0-1 (fp32); stage Ah0(t+1) -> AFP(a2)
    #pragma unroll
    for (int bn = 0; bn < 4; ++bn)
      #pragma unroll
      for (int kk = 0; kk < 2; ++kk)
        bf[bn][kk] = ld_frag(Bl, rB0 + bn * 16 + ln15, kk * 32 + kof);
    #pragma unroll
    for (int am = 0; am < 2; ++am)
      #pragma unroll
      for (int kk = 0; kk < 2; ++kk) {
        const int rp = wm * 64 + am * 16 + ln15;
        const int s0 = (kk * 32 + kof) >> 2;
        af[am][kk] = pack8f(ld4f(Al0, rp, s0), ld4f(Al0, rp, s0 + 1));
      }
    stage_f32(Atile + tn * 64, 0, AFP(a2), tid);
    BAR();
    MFMA_PAIR(0)
    BAR();

    // q1: af am2-3 (h0); stage Bh0(t+1) -> BHP(a2); vmcnt(6) before barrier
    #pragma unroll
    for (int am = 0; am < 2; ++am)
      #pragma unroll
      for (int kk = 0; kk < 2; ++kk) {
        const int rp = wm * 64 + (2 + am) * 16 + ln15;
        const int s0 = (kk * 32 + kof) >> 2;
        af[am][kk] = pack8f(ld4f(Al0, rp, s0), ld4f(Al0, rp, s0 + 1));
      }
    stage_half(W + (long)(n0 + 0) * 1024 + tn * 64, 1024, BHP(a2), wave, lane);
    BAR();
    MFMA_PAIR(2)
    WAITV(6);   // drain Ah1(t) (4 oldest); leaves Ah0(t+1)+Bh0(t+1)
    BAR();

    // q2: af am4-5 (h1); stage Bh1(t+1) -> BHP(a0) THEN Ah1(t+1) -> AFP(a0)
    #pragma unroll
    for (int am = 0; am < 2; ++am)
      #pragma unroll
      for (int kk = 0; kk < 2; ++kk) {
        const int rp = wm * 64 + am * 16 + ln15;       // am&3 = 0,1
        const int s0 = (kk * 32 + kof) >> 2;
        af[am][kk] = pack8f(ld4f(Al1, rp, s0), ld4f(Al1, rp, s0 + 1));
      }
    stage_half(W + (long)(n0 + 128) * 1024 + tn * 64, 1024, BHP(a0), wave, lane);
    stage_f32(Atile + tn * 64, 1, AFP(a0), tid);
    BAR();
    MFMA_PAIR(4)
    BAR();

    // q3: af am6-7 (h1); vmcnt(4) at tile end (Ah1(t+1) stays in flight)
    #pragma unroll
    for (int am = 0; am < 2; ++am)
      #pragma unroll
      for (int kk = 0; kk < 2; ++kk) {
        const int rp = wm * 64 + (2 + am) * 16 + ln15; // am&3 = 2,3
        const int s0 = (kk * 32 + kof) >> 2;
        af[am][kk] = pack8f(ld4f(Al1, rp, s0), ld4f(Al1, rp, s0 + 1));
      }
    BAR();
    MFMA_PAIR(6)
    WAITV(4);
    BAR();

    const int tmp = a0; a0 = a2; a2 = a1; a1 = tmp;   // (a0,a1,a2) <- (a2,a0,a1)
  }

  WAITV(0);
  BAR();   // all staging + LDS reads done; LDS free for epilogue transpose

  const int cl = lane & 15;
  const int rb = (lane >> 4) * 4;

  if (s.z < 2) {
    // bf16 row-major into qkb slab z via per-wave LDS transpose
    u16* Wt = lds + wave * 8192;
    #pragma unroll
    for (int am = 0; am < 8; ++am)
      #pragma unroll
      for (int bn = 0; bn < 4; ++bn) {
        const int col = bn * 16 + cl;
        const float badd = bias[n0 + wn * 64 + col];
        #pragma unroll
        for (int r = 0; r < 4; ++r) {
          const int row = am * 16 + rb + r;
          const int slot = (col >> 3) ^ ((row >> 2) & 7);
          Wt[row * 64 + slot * 8 + (col & 7)] = f2bf(acc[am][bn][r] + badd);
        }
      }
    WAITLGKM0();
    u16* Cp = qkb + (long)s.z * 16777216L;
    #pragma unroll
    for (int i = 0; i < 16; ++i) {
      const int row = (lane >> 3) + i * 8;
      const int c = lane & 7;
      const int slot = c ^ ((row >> 2) & 7);
      frag_ab v = *reinterpret_cast<const frag_ab*>(Wt + row * 64 + slot * 8);
      const long grow = m0 + wm * 128 + row;
      const int gcol = n0 + wn * 64 + c * 8;
      *reinterpret_cast<frag_ab*>(Cp + grow * 1024 + gcol) = v;
    }
  } else {
    // vT[b][gcol][l2]; 4 consecutive rows contiguous -> ushort4
    #pragma unroll
    for (int bn = 0; bn < 4; ++bn) {
      const int gcol = n0 + wn * 64 + bn * 16 + cl;
      const float badd = bias[gcol];
      #pragma unroll
      for (int am = 0; am < 8; ++am) {
        const int grow0 = m0 + wm * 128 + am * 16 + rb;
        ushort4 pk;
        pk.x = f2bf(acc[am][bn][0] + badd);
        pk.y = f2bf(acc[am][bn][1] + badd);
        pk.z = f2bf(acc[am][bn][2] + badd);
        pk.w = f2bf(acc[am][bn][3] + badd);
        const int bb = grow0 >> 11, l2 = grow0 & 2047;
        *reinterpret_cast<ushort4*>(vT + ((long)bb * 1024 + gcol) * 2048L + l2) = pk;
      }
    }
  }
}

// softmax over fp16 S slab: blockIdx.x = row; mask batch = row>>11
__global__ void softmax_rows_h(const u16* __restrict__ S, const int* __restrict__ Km,
                               u16* __restrict__ P)
{
  const long row = blockIdx.x;
  const int b = (int)(row >> 11);
  const u16* s = S + row * 2048;
  const int* mask = Km + (long)b * 2048;
  u16* p = P + row * 2048;

  const int t = threadIdx.x;
  const int base = t * 8;

  ushort4 r0 = *reinterpret_cast<const ushort4*>(s + base);
  ushort4 r1 = *reinterpret_cast<const ushort4*>(s + base + 4);
  int4 mA = *reinterpret_cast<const int4*>(mask + base);
  int4 mB = *reinterpret_cast<const int4*>(mask + base + 4);

  float vals[8] = {h2f(r0.x), h2f(r0.y), h2f(r0.z), h2f(r0.w),
                   h2f(r1.x), h2f(r1.y), h2f(r1.z), h2f(r1.w)};
  const int mk[8] = {mA.x, mA.y, mA.z, mA.w, mB.x, mB.y, mB.z, mB.w};

  float mx = -3.0e38f;
  #pragma unroll
  for (int i = 0; i < 8; i++) if (!mk[i]) mx = fmaxf(mx, vals[i]);
  #pragma unroll
  for (int off = 32; off > 0; off >>= 1) mx = fmaxf(mx, __shfl_xor(mx, off));

  __shared__ float redm[4], reds[4];
  const int wave = t >> 6, lane = t & 63;
  if (lane == 0) redm[wave] = mx;
  __syncthreads();
  mx = fmaxf(fmaxf(redm[0], redm[1]), fmaxf(redm[2], redm[3]));

  float e[8]; float sum = 0.f;
  #pragma unroll
  for (int i = 0; i < 8; i++) { e[i] = mk[i] ? 0.f : __expf(vals[i] - mx); sum += e[i]; }
  #pragma unroll
  for (int off = 32; off > 0; off >>= 1) sum += __shfl_xor(sum, off);
  if (lane == 0) reds[wave] = sum;
  __syncthreads();
  sum = reds[0] + reds[1] + reds[2] + reds[3];
  const float inv = 1.f / sum;

  *reinterpret_cast<ushort4*>(p + base) =
      make_ushort4(f2bf(e[0]*inv), f2bf(e[1]*inv), f2bf(e[2]*inv), f2bf(e[3]*inv));
  *reinterpret_cast<ushort4*>(p + base + 4) =
      make_ushort4(f2bf(e[4]*inv), f2bf(e[5]*inv), f2bf(e[6]*inv), f2bf(e[7]*inv));
}

extern "C" void kernel_launch(void* const* d_in, const int* in_sizes, int n_in,
                              void* d_out, int out_size, void* d_ws, size_t ws_size,
                              hipStream_t stream) {
  (void)in_sizes; (void)n_in; (void)out_size;

  const float* Qin  = (const float*)d_in[0];
  const float* Kin  = (const float*)d_in[1];
  const float* Vin  = (const float*)d_in[2];
  const int*   Kmask = (const int*)d_in[3];
  const float* Wq = (const float*)d_in[4];
  const float* bq = (const float*)d_in[5];
  const float* Wk = (const float*)d_in[6];
  const float* bk = (const float*)d_in[7];
  const float* Wv = (const float*)d_in[8];
  const float* bv = (const float*)d_in[9];

  char* ws = (char*)d_ws;
  const size_t MB = 1024UL * 1024UL;
  const dim3 blk(256);
  const dim3 gblk(512);
  const float rs = 0.03125f;  // 1/sqrt(1024)

  if (ws_size >= 226 * MB) {
    // [0,32) qb  [32,64) kb  [64,96) vT  [96,160) P  [160,224) S fp16(8 batches)
    // [224,230) Wb
    u16*  qb = (u16*)(ws);
    u16*  vT = (u16*)(ws + 64 * MB);
    u16*  P  = (u16*)(ws + 96 * MB);
    u16*  S  = (u16*)(ws + 160 * MB);
    u16*  Wb = (u16*)(ws + 224 * MB);

    cvtw3<<<dim3(1024, 1, 3), blk, 0, stream>>>(Wq, Wk, Wv, Wb);
    proj3f_gemm<<<dim3(4, 64, 3), gblk, 0, stream>>>(Qin, Kin, Vin, Wb,
        bq, bk, bv, qb, vT);

    qk_gemm<<<dim3(8, 8, 8), gblk, 0, stream>>>(qb, qb + 16777216L, S,
        2048, 2048, 1024, 2048L * 1024, 2048L * 1024, 2048L * 2048, rs);
    softmax_rows_h<<<dim3(16384), blk, 0, stream>>>(S, Kmask, P);

    pv_gemm<<<dim3(4, 8, 8), gblk, 0, stream>>>(P, vT, d_out,
        2048, 1024, 2048, 2048L * 2048, 1024L * 2048, 2048L * 1024, 1.f);
  } else if (ws_size >= 182 * MB) {
    // [0,64) qb/kb  [64,96) vT  [96,160) P  [160,176) S fp16(2 batches)
    // [176,182) Wb
    u16*  qb = (u16*)(ws);
    u16*  vT = (u16*)(ws + 64 * MB);
    u16*  P  = (u16*)(ws + 96 * MB);
    u16*  S  = (u16*)(ws + 160 * MB);
    u16*  Wb = (u16*)(ws + 176 * MB);

    cvtw3<<<dim3(1024, 1, 3), blk, 0, stream>>>(Wq, Wk, Wv, Wb);
    proj3f_gemm<<<dim3(4, 64, 3), gblk, 0, stream>>>(Qin, Kin, Vin, Wb,
        bq, bk, bv, qb, vT);

    for (int h = 0; h < 4; h++) {
      const u16* qbH = qb + (long)(2 * h) * 2048 * 1024;
      const u16* kbH = qb + 16777216L + (long)(2 * h) * 2048 * 1024;
      qk_gemm<<<dim3(8, 8, 2), gblk, 0, stream>>>(qbH, kbH, S,
          2048, 2048, 1024, 2048L * 1024, 2048L * 1024, 2048L * 2048, rs);
      softmax_rows_h<<<dim3(4096), blk, 0, stream>>>(
          S, Kmask + (long)(2 * h) * 2048, P + (long)(2 * h) * 2048 * 2048);
    }

    pv_gemm<<<dim3(4, 8, 8), gblk, 0, stream>>>(P, vT, d_out,
        2048, 1024, 2048, 2048L * 2048, 1024L * 2048, 2048L * 1024, 1.f);
  } else {
    // 118 MB fallback: per-batch S/P streaming
    u16*  qb = (u16*)(ws);                    // 64 MB (q + k slabs)
    u16*  vT = (u16*)(ws + 64 * MB);          // 32 MB
    u16*  S  = (u16*)(ws + 96 * MB);          //  8 MB fp16
    u16*  P  = (u16*)(ws + 104 * MB);         //  8 MB bf16
    u16*  Wb = (u16*)(ws + 112 * MB);         //  6 MB

    cvtw3<<<dim3(1024, 1, 3), blk, 0, stream>>>(Wq, Wk, Wv, Wb);
    proj3f_gemm<<<dim3(4, 64, 3), gblk, 0, stream>>>(Qin, Kin, Vin, Wb,
        bq, bk, bv, qb, vT);

    for (int b = 0; b < 8; b++) {
      const u16* qbB = qb + (long)b * 2048 * 1024;
      const u16* kbB = qb + 16777216L + (long)b * 2048 * 1024;
      const u16* vTB = vT + (long)b * 1024 * 2048;
      float* outB = (float*)d_out + (long)b * 2048 * 1024;

      qk_gemm<<<dim3(8, 8, 1), gblk, 0, stream>>>(qbB, kbB, S,
          2048, 2048, 1024, 0, 0, 0, rs);
      softmax_rows_h<<<dim3(2048), blk, 0, stream>>>(S, Kmask + (long)b * 2048, P);
      pv_gemm<<<dim3(4, 8, 1), gblk, 0, stream>>>(P, vTB, outB,
          2048, 1024, 2048, 0, 0, 0, 1.f);
    }
  }
}

// Round 13
// 330.103 us; speedup vs baseline: 1.1287x; 1.1287x over previous
//
#include <hip/hip_runtime.h>

// ---------------------------------------------------------------------------
// ScaleDotProductAttention: q=Q@Wq^T+bq; k=K@Wk^T+bk; v=V@Wv^T+bv
// S = q@k^T/32 (mask==1 -> -inf), P=softmax(S), out = P@v
// B=8, L1=L2=2048, D=E=1024. bf16 MFMA 16x16x32, fp32 accum.
// Round 13: REVERT to the round-11 configuration (best measured: 330us).
// Round-12's fp32-LDS staging was the third fused-convert failure (230us
// proj, 1.4e7 bank conflicts); the separate convert pass runs at BW roofline
// and the bf16 global_load_lds GEMM path is this structure's optimum.
// Components: 256x256 8-wave GEMM (XOR-swizzled LDS, 1-1-1-1 staging,
// counted vmcnt), LDS-transpose epilogues (ideal WRITE_SIZE), fp16 S,
// single-dispatch qk/softmax/pv, merged z=3 projections, XCD swizzle.
// ---------------------------------------------------------------------------

using u16 = unsigned short;
using frag_ab = __attribute__((ext_vector_type(8))) short;   // 8 bf16 (4 VGPRs)
using frag_cd = __attribute__((ext_vector_type(4))) float;   // 4 fp32

#define BAR() asm volatile("s_barrier" ::: "memory")
#define WAITV(n) asm volatile("s_waitcnt vmcnt(" #n ")" ::: "memory")
#define WAITLGKM0() do { asm volatile("s_waitcnt lgkmcnt(0)" ::: "memory"); \
                         __builtin_amdgcn_sched_barrier(0); } while (0)
#define HINT_LGKM8() asm volatile("s_waitcnt lgkmcnt(8)" ::: "memory")
#define L(d, ab, h) (lds + (((d) * 4) + ((ab) * 2) + (h)) * 8192)

__device__ __forceinline__ u16 f2bf(float f) {
  union { float f; unsigned u; } c; c.f = f;
  unsigned u = c.u;
  return (u16)((u + 0x7FFFu + ((u >> 16) & 1u)) >> 16);   // RNE
}
__device__ __forceinline__ u16 f2h(float f) {
  union { _Float16 h; u16 u; } c; c.h = (_Float16)f; return c.u;
}
__device__ __forceinline__ float h2f(u16 u) {
  union { u16 u; _Float16 h; } c; c.u = u; return (float)c.h;
}

__device__ __forceinline__ void async_ld16(const void* g, void* l) {
  __builtin_amdgcn_global_load_lds(
      (const __attribute__((address_space(1))) unsigned*)g,
      (__attribute__((address_space(3))) unsigned*)l, 16, 0, 0);
}

// weights fp32 -> bf16, one 3-way dispatch
__global__ void cvtw3(const float* __restrict__ a, const float* __restrict__ b,
                      const float* __restrict__ c, u16* __restrict__ out) {
  const float* in = blockIdx.z == 0 ? a : (blockIdx.z == 1 ? b : c);
  u16* o = out + (long)blockIdx.z * 1048576L;
  long i = ((long)blockIdx.x * 256 + threadIdx.x) * 4;
  float4 v = *reinterpret_cast<const float4*>(in + i);
  *reinterpret_cast<ushort4*>(o + i) =
      make_ushort4(f2bf(v.x), f2bf(v.y), f2bf(v.z), f2bf(v.w));
}

// Q,K,V inputs fp32 -> bf16 in one dispatch; dest stride 16M elements
__global__ void cvt3_f32_bf16(const float* __restrict__ q, const float* __restrict__ k,
                              const float* __restrict__ v, u16* __restrict__ out) {
  const float* in = blockIdx.z == 0 ? q : (blockIdx.z == 1 ? k : v);
  u16* o = out + (long)blockIdx.z * 16777216L;
  long i = ((long)blockIdx.x * 256 + threadIdx.x) * 4;
  float4 x = *reinterpret_cast<const float4*>(in + i);
  *reinterpret_cast<ushort4*>(o + i) =
      make_ushort4(f2bf(x.x), f2bf(x.y), f2bf(x.z), f2bf(x.w));
}

// Stage one 128x64 bf16 half-tile via global_load_lds (linear dest,
// 3-bit XOR swizzle pre-applied to the GLOBAL source 16B-slot).
__device__ __forceinline__ void stage_half(const u16* __restrict__ g_rowbase,
                                           long Kstr, u16* l_half,
                                           int wave, int lane) {
  const int t = wave * 64 + lane;
  #pragma unroll
  for (int i = 0; i < 2; i++) {
    const int row = i * 64 + (t >> 3);
    const int cb  = (t & 7) * 16;
    const int cbs = cb ^ ((row & 7) << 4);
    async_ld16(g_rowbase + (long)row * Kstr + (cbs >> 1),
               l_half + i * 4096 + wave * 512);
  }
}

// swizzled fragment read: 8 bf16 at (row r, k..k+7) of a [128][64] half
__device__ __forceinline__ frag_ab ld_frag(const u16* half_base, int r, int k) {
  const int idx = r * 64 + (k ^ ((r & 7) << 3));
  return *reinterpret_cast<const frag_ab*>(half_base + idx);
}

// Bijective XCD swizzle over the FULL grid (z folded in)
struct SwzOut { int z, m0, n0; };
__device__ __forceinline__ SwzOut grid_swizzle() {
  const int gx = gridDim.x, gy = gridDim.y, gz = gridDim.z;
  const int nwg = gx * gy * gz;
  const int lin = ((int)blockIdx.z * gy + blockIdx.y) * gx + blockIdx.x;
  const int q8 = nwg >> 3, r8 = nwg & 7;
  const int xcd = lin & 7, idx8 = lin >> 3;
  const int swz = (xcd < r8 ? xcd * (q8 + 1) : r8 * (q8 + 1) + (xcd - r8) * q8) + idx8;
  SwzOut o;
  o.z = swz / (gx * gy);
  const int rem = swz % (gx * gy);
  o.m0 = (rem / gx) * 256;
  o.n0 = (rem % gx) * 256;
  return o;
}

// C = scale * (A @ Bt^T) + bias, one 256x256 tile at (m0, n0).
// out_mode: 0 fp32 row-major; 1 bf16 row-major; 3 fp16 row-major
//           (all via LDS-transpose, 16B/lane stores);
//           2 bf16 vT[b][gcol][l2] with b=grow>>11 (packed ushort4).
// Cb is already z-offset for modes 0/1/3; global vT base for mode 2.
// K-loop: BK=64, 8 waves (2M x 4N), 128KB LDS dbuf, ds_reads 12/4/4/4,
// staging 1 half-tile per phase (q0,q1: A(t+1); q2,q3: B(t+2)), vmcnt(4)/tile.
__device__ __forceinline__ void
gemm256_core(int out_mode, const u16* __restrict__ Ab, const u16* __restrict__ Bb,
             void* __restrict__ Cb, const float* __restrict__ bias,
             int N, int K, int m0, int n0, float scale, u16* lds)
{
  const int tid = threadIdx.x;
  const int wave = tid >> 6, lane = tid & 63;
  const int wm = wave >> 2, wn = wave & 3;
  const int ln15 = lane & 15, kof = (lane >> 4) * 8;
  const int rB0 = (wn & 1) * 64;
  const int NT = K >> 6;

  frag_cd acc[8][4];
  #pragma unroll
  for (int i = 0; i < 8; i++)
    #pragma unroll
    for (int j = 0; j < 4; j++)
      acc[i][j] = (frag_cd){0.f, 0.f, 0.f, 0.f};

  // prologue: A(0),B(0) -> dbuf0; B(1) -> dbuf1; drain A0/B0 (B1 in flight)
  stage_half(Ab + (long)(m0 +   0) * K, K, L(0, 0, 0), wave, lane);
  stage_half(Ab + (long)(m0 + 128) * K, K, L(0, 0, 1), wave, lane);
  stage_half(Bb + (long)(n0 +   0) * K, K, L(0, 1, 0), wave, lane);
  stage_half(Bb + (long)(n0 + 128) * K, K, L(0, 1, 1), wave, lane);
  {
    const int t1 = (1 < NT) ? 1 : 0;
    stage_half(Bb + (long)(n0 +   0) * K + t1 * 64, K, L(1, 1, 0), wave, lane);
    stage_half(Bb + (long)(n0 + 128) * K + t1 * 64, K, L(1, 1, 1), wave, lane);
  }
  WAITV(4);
  BAR();

  for (int t = 0; t < NT; ++t) {
    const int d = t & 1;
    const u16* Al = L(d, 0, wm);
    const u16* Bl = L(d, 1, wn >> 1);
    const int tA = (t + 1 < NT) ? t + 1 : NT - 1;
    const int tB = (t + 2 < NT) ? t + 2 : NT - 1;

    frag_ab bf[4][2], af[2][2];

    // q0: 12 ds_reads; stage A(t+1) h0; lgkm hint; mfma am0-1
    #pragma unroll
    for (int bn = 0; bn < 4; ++bn)
      #pragma unroll
      for (int kk = 0; kk < 2; ++kk)
        bf[bn][kk] = ld_frag(Bl, rB0 + bn * 16 + ln15, kk * 32 + kof);
    #pragma unroll
    for (int am = 0; am < 2; ++am)
      #pragma unroll
      for (int kk = 0; kk < 2; ++kk)
        af[am][kk] = ld_frag(Al, am * 16 + ln15, kk * 32 + kof);
    stage_half(Ab + (long)(m0 + 0) * K + tA * 64, K, L(d ^ 1, 0, 0), wave, lane);
    HINT_LGKM8();
    BAR();
    __builtin_amdgcn_s_setprio(1);
    #pragma unroll
    for (int am = 0; am < 2; ++am)
      #pragma unroll
      for (int bn = 0; bn < 4; ++bn)
        #pragma unroll
        for (int kk = 0; kk < 2; ++kk)
          acc[am][bn] = __builtin_amdgcn_mfma_f32_16x16x32_bf16(af[am][kk], bf[bn][kk], acc[am][bn], 0, 0, 0);
    __builtin_amdgcn_s_setprio(0);
    BAR();

    // q1: 4 ds_reads; stage A(t+1) h1; mfma am2-3
    #pragma unroll
    for (int am = 0; am < 2; ++am)
      #pragma unroll
      for (int kk = 0; kk < 2; ++kk)
        af[am][kk] = ld_frag(Al, (2 + am) * 16 + ln15, kk * 32 + kof);
    stage_half(Ab + (long)(m0 + 128) * K + tA * 64, K, L(d ^ 1, 0, 1), wave, lane);
    BAR();
    __builtin_amdgcn_s_setprio(1);
    #pragma unroll
    for (int am = 0; am < 2; ++am)
      #pragma unroll
      for (int bn = 0; bn < 4; ++bn)
        #pragma unroll
        for (int kk = 0; kk < 2; ++kk)
          acc[2 + am][bn] = __builtin_amdgcn_mfma_f32_16x16x32_bf16(af[am][kk], bf[bn][kk], acc[2 + am][bn], 0, 0, 0);
    __builtin_amdgcn_s_setprio(0);
    BAR();

    // q2: 4 ds_reads; stage B(t+2) h0; mfma am4-5
    #pragma unroll
    for (int am = 0; am < 2; ++am)
      #pragma unroll
      for (int kk = 0; kk < 2; ++kk)
        af[am][kk] = ld_frag(Al, (4 + am) * 16 + ln15, kk * 32 + kof);
    stage_half(Bb + (long)(n0 + 0) * K + tB * 64, K, L(d, 1, 0), wave, lane);
    BAR();
    __builtin_amdgcn_s_setprio(1);
    #pragma unroll
    for (int am = 0; am < 2; ++am)
      #pragma unroll
      for (int bn = 0; bn < 4; ++bn)
        #pragma unroll
        for (int kk = 0; kk < 2; ++kk)
          acc[4 + am][bn] = __builtin_amdgcn_mfma_f32_16x16x32_bf16(af[am][kk], bf[bn][kk], acc[4 + am][bn], 0, 0, 0);
    __builtin_amdgcn_s_setprio(0);
    BAR();

    // q3: 4 ds_reads; stage B(t+2) h1; mfma am6-7; vmcnt(4)
    #pragma unroll
    for (int am = 0; am < 2; ++am)
      #pragma unroll
      for (int kk = 0; kk < 2; ++kk)
        af[am][kk] = ld_frag(Al, (6 + am) * 16 + ln15, kk * 32 + kof);
    stage_half(Bb + (long)(n0 + 128) * K + tB * 64, K, L(d, 1, 1), wave, lane);
    BAR();
    __builtin_amdgcn_s_setprio(1);
    #pragma unroll
    for (int am = 0; am < 2; ++am)
      #pragma unroll
      for (int bn = 0; bn < 4; ++bn)
        #pragma unroll
        for (int kk = 0; kk < 2; ++kk)
          acc[6 + am][bn] = __builtin_amdgcn_mfma_f32_16x16x32_bf16(af[am][kk], bf[bn][kk], acc[6 + am][bn], 0, 0, 0);
    __builtin_amdgcn_s_setprio(0);
    WAITV(4);   // drains A(t+1)+B(t+1); B(t+2) (4 newest) stays in flight
    BAR();
  }

  WAITV(0);
  BAR();   // staging drained, all waves past K-loop: LDS free for transpose

  const int cl = lane & 15;
  const int rb = (lane >> 4) * 4;

  if (out_mode == 1 || out_mode == 3) {
    // 2-byte row-major output via per-wave LDS transpose
    u16* Wt = lds + wave * 8192;
    #pragma unroll
    for (int am = 0; am < 8; ++am)
      #pragma unroll
      for (int bn = 0; bn < 4; ++bn) {
        const int col = bn * 16 + cl;
        const float badd = bias ? bias[n0 + wn * 64 + col] : 0.f;
        #pragma unroll
        for (int r = 0; r < 4; ++r) {
          const int row = am * 16 + rb + r;
          const int slot = (col >> 3) ^ ((row >> 2) & 7);
          const float val = acc[am][bn][r] * scale + badd;
          Wt[row * 64 + slot * 8 + (col & 7)] = (out_mode == 1) ? f2bf(val) : f2h(val);
        }
      }
    WAITLGKM0();
    u16* Cp = (u16*)Cb;
    #pragma unroll
    for (int i = 0; i < 16; ++i) {
      const int row = (lane >> 3) + i * 8;
      const int c = lane & 7;
      const int slot = c ^ ((row >> 2) & 7);
      frag_ab v = *reinterpret_cast<const frag_ab*>(Wt + row * 64 + slot * 8);
      const long grow = m0 + wm * 128 + row;
      const int gcol = n0 + wn * 64 + c * 8;
      *reinterpret_cast<frag_ab*>(Cp + grow * N + gcol) = v;
    }
  } else if (out_mode == 0) {
    // fp32 row-major output, 2 passes of 32 cols through LDS
    float* Wt = (float*)(void*)lds + wave * 4096;
    float* Cp = (float*)Cb;
    #pragma unroll
    for (int p = 0; p < 2; ++p) {
      #pragma unroll
      for (int am = 0; am < 8; ++am)
        #pragma unroll
        for (int bn = 0; bn < 2; ++bn) {
          const int col = bn * 16 + cl;
          #pragma unroll
          for (int r = 0; r < 4; ++r) {
            const int row = am * 16 + rb + r;
            const int slot = (col >> 2) ^ ((row >> 2) & 7);
            Wt[row * 32 + slot * 4 + (col & 3)] = acc[am][2 * p + bn][r] * scale;
          }
        }
      WAITLGKM0();
      #pragma unroll
      for (int i = 0; i < 16; ++i) {
        const int row = (lane >> 3) + i * 8;
        const int c = lane & 7;
        const int slot = c ^ ((row >> 2) & 7);
        float4 v = *reinterpret_cast<const float4*>(Wt + row * 32 + slot * 4);
        const long grow = m0 + wm * 128 + row;
        const int gcol = n0 + wn * 64 + p * 32 + c * 4;
        *reinterpret_cast<float4*>(Cp + grow * N + gcol) = v;
      }
      if (p == 0) WAITLGKM0();
    }
  } else {
    // out_mode 2: vT[b][gcol][l2]; 4 consecutive rows contiguous -> ushort4
    #pragma unroll
    for (int bn = 0; bn < 4; ++bn) {
      const int gcol = n0 + wn * 64 + bn * 16 + cl;
      const float badd = bias ? bias[gcol] : 0.f;
      #pragma unroll
      for (int am = 0; am < 8; ++am) {
        const int grow0 = m0 + wm * 128 + am * 16 + rb;
        ushort4 pk;
        pk.x = f2bf(acc[am][bn][0] * scale + badd);
        pk.y = f2bf(acc[am][bn][1] * scale + badd);
        pk.z = f2bf(acc[am][bn][2] * scale + badd);
        pk.w = f2bf(acc[am][bn][3] * scale + badd);
        const int bb = grow0 >> 11, l2 = grow0 & 2047;
        *reinterpret_cast<ushort4*>((u16*)Cb + ((long)bb * N + gcol) * 2048L + l2) = pk;
      }
    }
  }
}

// All three projections in one z=3 dispatch: z selects input/weight/bias;
// z<2 -> bf16 row-major into qkb slab z; z==2 -> vT packed.
__global__ void __launch_bounds__(512, 2)
proj3_gemm(const u16* __restrict__ X, const u16* __restrict__ Wb,
           const float* __restrict__ bq, const float* __restrict__ bk,
           const float* __restrict__ bv, u16* __restrict__ qkb,
           u16* __restrict__ vT)
{
  __shared__ u16 lds[8 * 8192];
  SwzOut s = grid_swizzle();
  const u16* A = X + (long)s.z * 16777216L;
  const u16* W = Wb + (long)s.z * 1048576L;
  const float* bias = s.z == 0 ? bq : (s.z == 1 ? bk : bv);
  if (s.z < 2)
    gemm256_core(1, A, W, qkb + (long)s.z * 16777216L, bias,
                 1024, 1024, s.m0, s.n0, 1.f, lds);
  else
    gemm256_core(2, A, W, vT, bias, 1024, 1024, s.m0, s.n0, 1.f, lds);
}

// single projection with explicit mode (fallback path)
__global__ void __launch_bounds__(512, 2)
proj1_gemm(int mode, const u16* A, const u16* W, void* C, const float* bias) {
  __shared__ u16 lds[8 * 8192];
  SwzOut s = grid_swizzle();
  gemm256_core(mode, A, W, C, bias, 1024, 1024, s.m0, s.n0, 1.f, lds);
}

__global__ void __launch_bounds__(512, 2)
qk_gemm(const u16* A, const u16* Bt, void* C,
        int M, int N, int K, long sA, long sB, long sC, float scale) {
  __shared__ u16 lds[8 * 8192];
  SwzOut s = grid_swizzle();
  gemm256_core(3, A + (long)s.z * sA, Bt + (long)s.z * sB,
               (u16*)C + (long)s.z * sC, nullptr, N, K, s.m0, s.n0, scale, lds);
}
__global__ void __launch_bounds__(512, 2)
pv_gemm(const u16* A, const u16* Bt, void* C,
        int M, int N, int K, long sA, long sB, long sC, float scale) {
  __shared__ u16 lds[8 * 8192];
  SwzOut s = grid_swizzle();
  gemm256_core(0, A + (long)s.z * sA, Bt + (long)s.z * sB,
               (float*)C + (long)s.z * sC, nullptr, N, K, s.m0, s.n0, scale, lds);
}

// softmax over fp16 S slab: blockIdx.x = row; mask batch = row>>11
__global__ void softmax_rows_h(const u16* __restrict__ S, const int* __restrict__ Km,
                               u16* __restrict__ P)
{
  const long row = blockIdx.x;
  const int b = (int)(row >> 11);
  const u16* s = S + row * 2048;
  const int* mask = Km + (long)b * 2048;
  u16* p = P + row * 2048;

  const int t = threadIdx.x;
  const int base = t * 8;

  ushort4 r0 = *reinterpret_cast<const ushort4*>(s + base);
  ushort4 r1 = *reinterpret_cast<const ushort4*>(s + base + 4);
  int4 mA = *reinterpret_cast<const int4*>(mask + base);
  int4 mB = *reinterpret_cast<const int4*>(mask + base + 4);

  float vals[8] = {h2f(r0.x), h2f(r0.y), h2f(r0.z), h2f(r0.w),
                   h2f(r1.x), h2f(r1.y), h2f(r1.z), h2f(r1.w)};
  const int mk[8] = {mA.x, mA.y, mA.z, mA.w, mB.x, mB.y, mB.z, mB.w};

  float mx = -3.0e38f;
  #pragma unroll
  for (int i = 0; i < 8; i++) if (!mk[i]) mx = fmaxf(mx, vals[i]);
  #pragma unroll
  for (int off = 32; off > 0; off >>= 1) mx = fmaxf(mx, __shfl_xor(mx, off));

  __shared__ float redm[4], reds[4];
  const int wave = t >> 6, lane = t & 63;
  if (lane == 0) redm[wave] = mx;
  __syncthreads();
  mx = fmaxf(fmaxf(redm[0], redm[1]), fmaxf(redm[2], redm[3]));

  float e[8]; float sum = 0.f;
  #pragma unroll
  for (int i = 0; i < 8; i++) { e[i] = mk[i] ? 0.f : __expf(vals[i] - mx); sum += e[i]; }
  #pragma unroll
  for (int off = 32; off > 0; off >>= 1) sum += __shfl_xor(sum, off);
  if (lane == 0) reds[wave] = sum;
  __syncthreads();
  sum = reds[0] + reds[1] + reds[2] + reds[3];
  const float inv = 1.f / sum;

  *reinterpret_cast<ushort4*>(p + base) =
      make_ushort4(f2bf(e[0]*inv), f2bf(e[1]*inv), f2bf(e[2]*inv), f2bf(e[3]*inv));
  *reinterpret_cast<ushort4*>(p + base + 4) =
      make_ushort4(f2bf(e[4]*inv), f2bf(e[5]*inv), f2bf(e[6]*inv), f2bf(e[7]*inv));
}

extern "C" void kernel_launch(void* const* d_in, const int* in_sizes, int n_in,
                              void* d_out, int out_size, void* d_ws, size_t ws_size,
                              hipStream_t stream) {
  (void)in_sizes; (void)n_in; (void)out_size;

  const float* Qin  = (const float*)d_in[0];
  const float* Kin  = (const float*)d_in[1];
  const float* Vin  = (const float*)d_in[2];
  const int*   Kmask = (const int*)d_in[3];
  const float* Wq = (const float*)d_in[4];
  const float* bq = (const float*)d_in[5];
  const float* Wk = (const float*)d_in[6];
  const float* bk = (const float*)d_in[7];
  const float* Wv = (const float*)d_in[8];
  const float* bv = (const float*)d_in[9];

  char* ws = (char*)d_ws;
  const size_t MB = 1024UL * 1024UL;
  const dim3 blk(256);
  const dim3 gblk(512);
  const float rs = 0.03125f;  // 1/sqrt(1024)

  if (ws_size >= 226 * MB) {
    // [0,32) qb  [32,64) kb  [64,96) vT
    // [96,160)  P bf16 / {Xq 96-128, Xk 128-160} during projections
    // [160,224) S fp16 all 8 batches / Xv 160-192 during projections
    // [224,230) Wb (3x 2MB)
    u16*  qb = (u16*)(ws);
    u16*  vT = (u16*)(ws + 64 * MB);
    u16*  P  = (u16*)(ws + 96 * MB);
    u16*  Xq = (u16*)(ws + 96 * MB);     // 3x 16M-elem slabs at 96/128/160
    u16*  S  = (u16*)(ws + 160 * MB);
    u16*  Wb = (u16*)(ws + 224 * MB);

    cvt3_f32_bf16<<<dim3(16384, 1, 3), blk, 0, stream>>>(Qin, Kin, Vin, Xq);
    cvtw3<<<dim3(1024, 1, 3), blk, 0, stream>>>(Wq, Wk, Wv, Wb);

    proj3_gemm<<<dim3(4, 64, 3), gblk, 0, stream>>>(Xq, Wb, bq, bk, bv, qb, vT);

    qk_gemm<<<dim3(8, 8, 8), gblk, 0, stream>>>(qb, qb + 16777216L, S,
        2048, 2048, 1024, 2048L * 1024, 2048L * 1024, 2048L * 2048, rs);
    softmax_rows_h<<<dim3(16384), blk, 0, stream>>>(S, Kmask, P);

    pv_gemm<<<dim3(4, 8, 8), gblk, 0, stream>>>(P, vT, d_out,
        2048, 1024, 2048, 2048L * 2048, 1024L * 2048, 2048L * 1024, 1.f);
  } else if (ws_size >= 194 * MB) {
    // S fp16 4 batches at 160-192 (Wb at 186-192: dead before S written)
    u16*  qb = (u16*)(ws);
    u16*  vT = (u16*)(ws + 64 * MB);
    u16*  P  = (u16*)(ws + 96 * MB);
    u16*  Xq = (u16*)(ws + 96 * MB);
    u16*  S  = (u16*)(ws + 160 * MB);
    u16*  Wb = (u16*)(ws + 186 * MB);

    cvt3_f32_bf16<<<dim3(16384, 1, 3), blk, 0, stream>>>(Qin, Kin, Vin, Xq);
    cvtw3<<<dim3(1024, 1, 3), blk, 0, stream>>>(Wq, Wk, Wv, Wb);

    proj3_gemm<<<dim3(4, 64, 3), gblk, 0, stream>>>(Xq, Wb, bq, bk, bv, qb, vT);

    for (int h = 0; h < 2; h++) {
      const u16* qbH = qb + (long)(4 * h) * 2048 * 1024;
      const u16* kbH = qb + 16777216L + (long)(4 * h) * 2048 * 1024;
      qk_gemm<<<dim3(8, 8, 4), gblk, 0, stream>>>(qbH, kbH, S,
          2048, 2048, 1024, 2048L * 1024, 2048L * 1024, 2048L * 2048, rs);
      softmax_rows_h<<<dim3(8192), blk, 0, stream>>>(
          S, Kmask + (long)(4 * h) * 2048, P + (long)(4 * h) * 2048 * 2048);
    }

    pv_gemm<<<dim3(4, 8, 8), gblk, 0, stream>>>(P, vT, d_out,
        2048, 1024, 2048, 2048L * 2048, 1024L * 2048, 2048L * 1024, 1.f);
  } else {
    // 130 MB fallback: per-input converts, per-batch S/P streaming
    u16*  qb = (u16*)(ws);
    u16*  kb = (u16*)(ws + 32 * MB);
    u16*  vT = (u16*)(ws + 64 * MB);
    u16*  Xb = (u16*)(ws + 96 * MB);
    u16*  S  = (u16*)(ws + 96 * MB);
    u16*  P  = (u16*)(ws + 104 * MB);
    u16*  Wb = (u16*)(ws + 128 * MB);

    cvtw3<<<dim3(1024, 1, 3), blk, 0, stream>>>(Wq, Wk, Wv, Wb);
    cvt3_f32_bf16<<<dim3(16384, 1, 1), blk, 0, stream>>>(Qin, Qin, Qin, Xb);
    proj1_gemm<<<dim3(4, 64, 1), gblk, 0, stream>>>(1, Xb, Wb, qb, bq);
    cvt3_f32_bf16<<<dim3(16384, 1, 1), blk, 0, stream>>>(Kin, Kin, Kin, Xb);
    proj1_gemm<<<dim3(4, 64, 1), gblk, 0, stream>>>(1, Xb, Wb + 1048576L, kb, bk);
    cvt3_f32_bf16<<<dim3(16384, 1, 1), blk, 0, stream>>>(Vin, Vin, Vin, Xb);
    proj1_gemm<<<dim3(4, 64, 1), gblk, 0, stream>>>(2, Xb, Wb + 2L * 1048576L, vT, bv);

    for (int b = 0; b < 8; b++) {
      const u16* qbB = qb + (long)b * 2048 * 1024;
      const u16* kbB = kb + (long)b * 2048 * 1024;
      const u16* vTB = vT + (long)b * 1024 * 2048;
      float* outB = (float*)d_out + (long)b * 2048 * 1024;

      qk_gemm<<<dim3(8, 8, 1), gblk, 0, stream>>>(qbB, kbB, S,
          2048, 2048, 1024, 0, 0, 0, rs);
      softmax_rows_h<<<dim3(2048), blk, 0, stream>>>(S, Kmask + (long)b * 2048, P);
      pv_gemm<<<dim3(4, 8, 1), gblk, 0, stream>>>(P, vTB, outB,
          2048, 1024, 2048, 0, 0, 0, 1.f);
    }
  }
}